// Round 10
// baseline (149.571 us; speedup 1.0000x reference)
//
#include <hip/hip_runtime.h>
#include <hip/hip_bf16.h>

// ---------------- types ----------------
typedef __bf16 bf16x8 __attribute__((ext_vector_type(8)));
typedef __bf16 bf16x4 __attribute__((ext_vector_type(4)));
typedef float  f32x4  __attribute__((ext_vector_type(4)));
typedef short  s16x4  __attribute__((ext_vector_type(4)));

__device__ __forceinline__ __bf16 to_bf16(float f) {
    __hip_bfloat16 h = __float2bfloat16(f);
    return *reinterpret_cast<__bf16*>(&h);
}

__device__ __forceinline__ f32x4 mfma32(bf16x8 a, bf16x8 b, f32x4 c) {
    return __builtin_amdgcn_mfma_f32_16x16x32_bf16(a, b, c, 0, 0, 0);
}
// 16x16x16 bf16 MFMA (PV): S^T C-layout == B-layout, so P^T feeds directly
__device__ __forceinline__ f32x4 mfma16(bf16x4 a, bf16x4 b, f32x4 c) {
#if __has_builtin(__builtin_amdgcn_mfma_f32_16x16x16_bf16)
    return __builtin_amdgcn_mfma_f32_16x16x16_bf16(a, b, c, 0, 0, 0);
#else
    return __builtin_amdgcn_mfma_f32_16x16x16bf16_1k(
        __builtin_bit_cast(s16x4, a), __builtin_bit_cast(s16x4, b), c, 0, 0, 0);
#endif
}

// async global->LDS, 16B per lane; lds ptr must be wave-uniform (GEMM only)
__device__ __forceinline__ void gload_lds16(const __bf16* g, __bf16* l) {
    __builtin_amdgcn_global_load_lds(
        (const __attribute__((address_space(1))) void*)g,
        (__attribute__((address_space(3))) void*)l, 16, 0, 0);
}

// constants: B=2, L=2048, DIM=1024, H=16, KVH=4, HD=64, REP=4

// ---------------- fused prep: 4 weight transposes + x cast ----------------
__global__ __launch_bounds__(256) void prep_k(const float* __restrict__ wq,
                                              const float* __restrict__ wk,
                                              const float* __restrict__ wv,
                                              const float* __restrict__ wo,
                                              const float* __restrict__ x,
                                              __bf16* __restrict__ WqkvT,
                                              __bf16* __restrict__ WoT,
                                              __bf16* __restrict__ xb) {
    int b = blockIdx.x, tid = threadIdx.x;
    if (b >= 2560) {
        int i = ((b - 2560) * 256 + tid) * 8;
        f32x4 a = *(const f32x4*)(x + i);
        f32x4 c = *(const f32x4*)(x + i + 4);
        bf16x8 h;
        h[0] = to_bf16(a.x); h[1] = to_bf16(a.y); h[2] = to_bf16(a.z); h[3] = to_bf16(a.w);
        h[4] = to_bf16(c.x); h[5] = to_bf16(c.y); h[6] = to_bf16(c.z); h[7] = to_bf16(c.w);
        *(bf16x8*)(xb + i) = h;
        return;
    }
    __shared__ float tile[32][33];
    const float* src; __bf16* dst; int N, idx;
    if (b < 1024)      { src = wq; dst = WqkvT;                        N = 1024; idx = b; }
    else if (b < 1280) { src = wk; dst = WqkvT + (size_t)1024 * 1024;  N = 256;  idx = b - 1024; }
    else if (b < 1536) { src = wv; dst = WqkvT + (size_t)1280 * 1024;  N = 256;  idx = b - 1280; }
    else               { src = wo; dst = WoT;                          N = 1024; idx = b - 1536; }
    int k0 = (idx & 31) * 32, n0 = (idx >> 5) * 32;
    int tx = tid & 31, ty = tid >> 5;
#pragma unroll
    for (int r = 0; r < 4; ++r) {
        int kk = ty + r * 8;
        tile[kk][tx] = src[(size_t)(k0 + kk) * N + n0 + tx];
    }
    __syncthreads();
#pragma unroll
    for (int r = 0; r < 4; ++r) {
        int nn = ty + r * 8;
        dst[(size_t)(n0 + nn) * 1024 + k0 + tx] = to_bf16(tile[tx][nn]);
    }
}

// ---- shared GEMM core: 128x64 tile, BK=64 (two 32-wide k-half LDS buffers;
//      stride-32 rows stay DMA-lane-linear AND bank-conflict-free) ----------
#define GEMM_CORE(A, BT, K)                                                     \
    __shared__ __bf16 lA[8192];                                                 \
    __shared__ __bf16 lB[4096];                                                 \
    int tid = threadIdx.x;                                                      \
    int m0 = blockIdx.x * 128, n0 = blockIdx.y * 64;                            \
    int wid = tid >> 6, lane = tid & 63;                                        \
    int wm = (wid & 1) * 64, wn = (wid >> 1) * 32;                              \
    int lm = lane & 15, qd = lane >> 4;                                         \
    f32x4 acc[4][2] = {};                                                       \
    for (int k0 = 0; k0 < (K); k0 += 64) {                                      \
        _Pragma("unroll")                                                       \
        for (int it = 0; it < 4; ++it) {                                        \
            int kh = it >> 1, half = it & 1;                                    \
            int c = half * 256 + tid;                                           \
            int row = c >> 2, c4 = c & 3;                                       \
            __bf16* la = lA + kh * 4096 + half * 2048 + wid * 512;              \
            gload_lds16((A) + (size_t)(m0 + row) * (K) + k0 + kh * 32 + c4 * 8, la); \
        }                                                                       \
        _Pragma("unroll")                                                       \
        for (int kh = 0; kh < 2; ++kh) {                                        \
            int row = tid >> 2, c4 = tid & 3;                                   \
            __bf16* lb = lB + kh * 2048 + wid * 512;                            \
            gload_lds16((BT) + (size_t)(n0 + row) * (K) + k0 + kh * 32 + c4 * 8, lb); \
        }                                                                       \
        __syncthreads();                                                        \
        _Pragma("unroll")                                                       \
        for (int kh = 0; kh < 2; ++kh) {                                        \
            bf16x8 af[4], bfr[2];                                               \
            _Pragma("unroll")                                                   \
            for (int t = 0; t < 4; ++t) {                                       \
                int row = wm + t * 16 + lm;                                     \
                af[t] = *(const bf16x8*)&lA[kh * 4096 + (row >> 6) * 2048       \
                                            + (row & 63) * 32 + qd * 8];        \
            }                                                                   \
            _Pragma("unroll")                                                   \
            for (int j = 0; j < 2; ++j)                                         \
                bfr[j] = *(const bf16x8*)&lB[kh * 2048 + (wn + j * 16 + lm) * 32 \
                                             + qd * 8];                         \
            _Pragma("unroll")                                                   \
            for (int ti = 0; ti < 4; ++ti)                                      \
                _Pragma("unroll")                                               \
                for (int tj = 0; tj < 2; ++tj)                                  \
                    acc[ti][tj] = mfma32(af[ti], bfr[tj], acc[ti][tj]);         \
        }                                                                       \
        __syncthreads();                                                        \
    }

// ------- fused QKV GEMM + RMSNorm + RoPE + layout write -------------------
__global__ __launch_bounds__(256) void gemmqkv_k(const __bf16* __restrict__ A,
                                                 const __bf16* __restrict__ BT,
                                                 const float* __restrict__ gq,
                                                 const float* __restrict__ gk,
                                                 __bf16* __restrict__ Qb,
                                                 __bf16* __restrict__ Kbl,
                                                 __bf16* __restrict__ Vt) {
    __shared__ float ssp[2][128];
    __shared__ __bf16 tv[64 * 136];
    GEMM_CORE(A, BT, 1024)
    int head = n0 >> 6;

    if (head < 20) {
#pragma unroll
        for (int ti = 0; ti < 4; ++ti)
#pragma unroll
            for (int r = 0; r < 4; ++r) {
                float sq = acc[ti][0][r] * acc[ti][0][r] + acc[ti][1][r] * acc[ti][1][r];
                sq += __shfl_xor(sq, 1);
                sq += __shfl_xor(sq, 2);
                sq += __shfl_xor(sq, 4);
                sq += __shfl_xor(sq, 8);
                if (lm == 0) ssp[wid >> 1][wm + ti * 16 + qd * 4 + r] = sq;
            }
        __syncthreads();

        bool isq = head < 16;
#pragma unroll
        for (int ti = 0; ti < 4; ++ti)
#pragma unroll
            for (int r = 0; r < 4; ++r) {
                int row = wm + ti * 16 + qd * 4 + r;
                int t = m0 + row;
                int pos = t & 2047, bb = t >> 11;
                float ss = ssp[0][row] + ssp[1][row];
                float scale = rsqrtf(ss * (1.0f / 64.0f) + 1e-6f);
#pragma unroll
                for (int tj = 0; tj < 2; ++tj) {
                    int col = wn + tj * 16 + lm;
                    float g = isq ? gq[col] : gk[col];
                    float v = acc[ti][tj][r] * scale * g;
                    float ex = (float)(2 * (col >> 1)) * (1.0f / 64.0f);
                    float invf = expf(-ex * 9.210340371976184f);
                    float ang = (float)pos * invf;
                    float c = cosf(ang), s = sinf(ang);
                    float pv = __shfl_xor(v, 1);
                    float outv = (col & 1) ? (pv * s + v * c) : (v * c - pv * s);
                    if (isq) {
                        int kvh = head >> 2, h4 = head & 3;
                        size_t off = (((((size_t)bb * 4 + kvh) * 128 + (pos >> 4)) * 4 + h4) * 16
                                      + (pos & 15)) * 64 + col;
                        Qb[off] = to_bf16(outv * 0.125f);
                    } else {
                        int kvg = head - 16;
                        Kbl[(((size_t)bb * 4 + kvg) * 2048 + pos) * 64 + col] = to_bf16(outv);
                    }
                }
            }
    } else {
#pragma unroll
        for (int ti = 0; ti < 4; ++ti)
#pragma unroll
            for (int tj = 0; tj < 2; ++tj)
#pragma unroll
                for (int r = 0; r < 4; ++r) {
                    int row = wm + ti * 16 + qd * 4 + r;
                    int col = wn + tj * 16 + lm;
                    tv[col * 136 + row] = to_bf16(acc[ti][tj][r]);
                }
        __syncthreads();
        int bb = m0 >> 11, kvg = head - 20;
        size_t gg = (size_t)bb * 4 + kvg;
        int pos0 = m0 & 2047;
#pragma unroll
        for (int p = 0; p < 4; ++p) {
            int d = p * 16 + (tid >> 4);
            int tok = (tid & 15) * 8;
            bf16x8 vvv = *(const bf16x8*)&tv[d * 136 + tok];
            *(bf16x8*)(Vt + (gg * 64 + d) * 2048 + pos0 + tok) = vvv;
        }
    }
}

// ---------------- generic GEMM 128x64 BK=64 (output projection) ---------------
__global__ __launch_bounds__(256) void gemm_bf16_k(const __bf16* __restrict__ A,
                                                   const __bf16* __restrict__ BT,
                                                   float* __restrict__ C,
                                                   int K, int N) {
    GEMM_CORE(A, BT, K)
#pragma unroll
    for (int ti = 0; ti < 4; ++ti)
#pragma unroll
        for (int tj = 0; tj < 2; ++tj)
#pragma unroll
            for (int r = 0; r < 4; ++r) {
                int row = m0 + wm + ti * 16 + qd * 4 + r;
                int col = n0 + wn + tj * 16 + lm;
                C[(size_t)row * N + col] = acc[ti][tj][r];
            }
}

// ---------------- MFMA flash attention, 64-query blocks, 16 waves --------------
// grid (32, 4, 2): block = (64 queries, kvh, b). 16 waves = 4 heads x 4 q-groups;
// K/V staged once per 64 queries (tiles/query ~halved vs 32q). Double-buffered
// XOR-swizzled LDS in one 32KB pool; epilogue reuses it for the O transpose.
// Fully-masked tiles for a wave are numerically inert (alpha=1, p=0).
__global__ __launch_bounds__(1024) void attn_k(const __bf16* __restrict__ Qb,
                                               const __bf16* __restrict__ Kbl,
                                               const __bf16* __restrict__ Vt,
                                               __bf16* __restrict__ aout) {
    __shared__ __bf16 SM[16384];        // [buf][K 4096 | V 4096]; epilogue: 16x1024
    int tid = threadIdx.x, wid = tid >> 6, lane = tid & 63;
    int l15 = lane & 15, quad = lane >> 4;
    int qb = blockIdx.x, kvh = blockIdx.y, b = blockIdx.z;
    int qg = wid >> 2;                  // query group 0..3
    int h4 = wid & 3;                   // head within group
    int iw0 = qb * 64;                  // block query base
    int iw = iw0 + qg * 16;             // wave query base
    int g = b * 4 + kvh;
    int h = kvh * 4 + h4;
    int e7 = l15 & 7;

    // Q^T B-frag straight from Qb (bf16, 1/8 pre-baked)
    int qbi = qb * 4 + qg;
    const __bf16* qp = Qb + ((((size_t)g * 128 + qbi) * 4 + h4) * 16 + l15) * 64 + quad * 8;
    bf16x8 qf0 = *(const bf16x8*)qp;
    bf16x8 qf1 = *(const bf16x8*)(qp + 32);

    int ts = (iw0 - 256) >> 6; if (ts < 1) ts = 1;
    int tmaxb = (iw0 + 63) >> 6;                       // block tile bound
    int n_all = (tmaxb >= ts) ? (tmaxb - ts + 2) : 1;  // [0] ++ [ts..tmaxb]
    int tmaxw = (iw + 15) >> 6;                        // wave mask bound

    const __bf16* Kg = Kbl + (size_t)g * 2048 * 64;
    const __bf16* Vg = Vt + (size_t)g * 64 * 2048;

    // staging: 1024 threads; tid<512 -> K chunk, tid>=512 -> V chunk (8 elems)
    int t2 = tid & 511;
    int r0 = t2 >> 3, c0 = t2 & 7;                     // rows 0..63
    bool isK = tid < 512;
    int kl = r0 * 64 + ((c0 ^ (r0 & 7)) * 8) + (isK ? 0 : 4096);

    bf16x8 sr;
    auto stage_load = [&](int tt) {
        sr = isK ? *(const bf16x8*)(Kg + (size_t)tt * 64 * 64 + r0 * 64 + c0 * 8)
                 : *(const bf16x8*)(Vg + (size_t)r0 * 2048 + tt * 64 + c0 * 8);
    };
    auto stage_write = [&](int buf) {
        *(bf16x8*)&SM[buf * 8192 + kl] = sr;
    };

    stage_load(0);
    stage_write(0);

    f32x4 o[4] = {};
    float mr = -1e30f, lrp = 0.f;
    int iq = iw + l15;

    for (int idx = 0; idx < n_all; ++idx) {
        int tt = (idx == 0) ? 0 : ts + idx - 1;
        if (idx + 1 < n_all) stage_load(ts + idx);
        __syncthreads();
        int buf = idx & 1;
        const __bf16* Kt = SM + buf * 8192;
        const __bf16* Vl = Kt + 4096;

        // QK^T: S^T (C layout: row=key=nt*16+quad*4+r, col=query=l15)
        f32x4 s[4] = {};
#pragma unroll
        for (int nt = 0; nt < 4; ++nt) {
            const __bf16* kp = &Kt[(nt * 16 + l15) * 64];
            bf16x8 k0 = *(const bf16x8*)(kp + ((quad ^ e7) * 8));
            bf16x8 k1 = *(const bf16x8*)(kp + (((quad + 4) ^ e7) * 8));
            s[nt] = mfma32(k0, qf0, s[nt]);
            s[nt] = mfma32(k1, qf1, s[nt]);
        }

        bool need_mask = (tt >= tmaxw) || (tt >= 1 && tt * 64 < iw + 15 - 256);
        if (need_mask) {
#pragma unroll
            for (int nt = 0; nt < 4; ++nt)
#pragma unroll
                for (int r = 0; r < 4; ++r) {
                    int j = tt * 64 + nt * 16 + quad * 4 + r;
                    bool valid = (j <= iq) && ((j >= iq - 256) || (j < 64));
                    s[nt][r] = valid ? s[nt][r] : -1e30f;
                }
        }

        float mx = -1e30f;
#pragma unroll
        for (int nt = 0; nt < 4; ++nt)
#pragma unroll
            for (int r = 0; r < 4; ++r) mx = fmaxf(mx, s[nt][r]);
        mx = fmaxf(mx, __shfl_xor(mx, 16));
        mx = fmaxf(mx, __shfl_xor(mx, 32));
        float mn = fmaxf(mr, mx);
        float alpha = __expf(mr - mn);
        mr = mn;

        float ps = 0.f;
        bf16x4 pb[4];
#pragma unroll
        for (int nt = 0; nt < 4; ++nt)
#pragma unroll
            for (int r = 0; r < 4; ++r) {
                float pv = __expf(s[nt][r] - mn);
                ps += pv;
                pb[nt][r] = to_bf16(pv);
            }
        lrp = lrp * alpha + ps;

        // PV: A = V^T frag from LDS, B = P^T (register-direct)
#pragma unroll
        for (int dt = 0; dt < 4; ++dt) {
            o[dt] *= alpha;
            const __bf16* vp = &Vl[(dt * 16 + l15) * 64];
#pragma unroll
            for (int nt = 0; nt < 4; ++nt) {
                int c8 = 2 * nt + (quad >> 1);
                bf16x4 va = *(const bf16x4*)(vp + ((c8 ^ e7) * 8) + (quad & 1) * 4);
                o[dt] = mfma16(va, pb[nt], o[dt]);
            }
        }

        if (idx + 1 < n_all) stage_write((idx + 1) & 1);
    }

    // epilogue: reduce l across quads, normalize, LDS transpose, 16B stores
    lrp += __shfl_xor(lrp, 16);
    lrp += __shfl_xor(lrp, 32);
    float inv = 1.f / lrp;
    __syncthreads();                            // done with K/V buffers
    __bf16* pr = SM + wid * 1024;               // 16 waves x 1024 elems = 32 KB
#pragma unroll
    for (int dt = 0; dt < 4; ++dt)
#pragma unroll
        for (int r = 0; r < 4; ++r) {
            int e = dt * 16 + quad * 4 + r;
            int c8 = e >> 3;
            pr[l15 * 64 + ((c8 ^ e7) * 8) + (e & 7)] = to_bf16(o[dt][r] * inv);
        }
    bf16x8 o0 = *(const bf16x8*)(pr + l15 * 64 + (((2 * quad) ^ e7) * 8));
    bf16x8 o1 = *(const bf16x8*)(pr + l15 * 64 + (((2 * quad + 1) ^ e7) * 8));
    __bf16* op = aout + ((size_t)b * 2048 + iw + l15) * 1024 + h * 64 + quad * 16;
    *(bf16x8*)op = o0;
    *(bf16x8*)(op + 8) = o1;
}

// ---------------- launch ----------------
extern "C" void kernel_launch(void* const* d_in, const int* in_sizes, int n_in,
                              void* d_out, int out_size, void* d_ws, size_t ws_size,
                              hipStream_t stream) {
    const float* x  = (const float*)d_in[0];
    const float* wq = (const float*)d_in[1];
    const float* wk = (const float*)d_in[2];
    const float* wv = (const float*)d_in[3];
    const float* wo = (const float*)d_in[4];
    const float* gq = (const float*)d_in[5];
    const float* gk = (const float*)d_in[6];
    float* out = (float*)d_out;

    char* ws = (char*)d_ws;
    __bf16* WqkvT = (__bf16*)ws;                         //  3145728 B
    __bf16* WoT   = (__bf16*)(ws + 3145728);             //  2097152 B
    __bf16* xb_ao = (__bf16*)(ws + 5242880);             //  8388608 B (xb, then aout)
    __bf16* Kbl   = (__bf16*)(ws + 13631488);            //  2097152 B
    __bf16* Vt    = (__bf16*)(ws + 15728640);            //  2097152 B
    __bf16* Qb    = (__bf16*)(ws + 17825792);            //  8388608 B -> total 26214400

    dim3 tb(256);
    prep_k<<<4608, tb, 0, stream>>>(wq, wk, wv, wo, x, WqkvT, WoT, xb_ao);
    gemmqkv_k<<<dim3(32, 24), tb, 0, stream>>>(xb_ao, WqkvT, gq, gk, Qb, Kbl, Vt);
    attn_k<<<dim3(32, 4, 2), dim3(1024), 0, stream>>>(Qb, Kbl, Vt, xb_ao);
    gemm_bf16_k<<<dim3(32, 16), tb, 0, stream>>>(xb_ao, WoT, out, 1024, 1024);
}